// Round 1
// baseline (42.787 us; speedup 1.0000x reference)
//
#include <hip/hip_runtime.h>

// STN bilinear sampling: B=16, H=W=256, C=32, out 256x256, fp32 NHWC.
// 8 lanes per output pixel, one float4 (4 channels) per lane.

constexpr int B  = 16;
constexpr int H  = 256;
constexpr int W  = 256;
constexpr int C  = 32;
constexpr int OH = 256;
constexpr int OW = 256;

__global__ __launch_bounds__(256) void stn_bilinear_kernel(
    const float* __restrict__ in,     // [B, H, W, C]
    const float* __restrict__ theta,  // [B, 6]
    float* __restrict__ out)          // [B, OH, OW, C]
{
    const int tid = blockIdx.x * 256 + threadIdx.x;
    const int p = tid >> 3;   // output pixel index in [0, B*OH*OW)
    const int q = tid & 7;    // channel quad (float4 index within pixel)

    // OH*OW = 65536 pixels per batch
    const int b   = p >> 16;
    const int rem = p & 65535;
    const int oy  = rem >> 8;
    const int ox  = rem & 255;

    // normalized grid coords: linspace(-1, 1, N) -> -1 + 2*i/(N-1)
    const float xs = -1.0f + (2.0f / (float)(OW - 1)) * (float)ox;
    const float ys = -1.0f + (2.0f / (float)(OH - 1)) * (float)oy;

    // affine transform (theta near-identity; scalar-cached loads, b uniform per block)
    const float* t = theta + b * 6;
    const float x = (t[0] * xs + t[1] * ys + t[2] + 1.0f) * (0.5f * (float)W);
    const float y = (t[3] * xs + t[4] * ys + t[5] + 1.0f) * (0.5f * (float)H);

    const float x0f = floorf(x);
    const float y0f = floorf(y);
    const float x1f = x0f + 1.0f;
    const float y1f = y0f + 1.0f;

    // gather indices: clipped. weights: from UNclipped floats (reference semantics).
    const int x0 = min(max((int)x0f, 0), W - 1);
    const int x1 = min(max((int)x1f, 0), W - 1);
    const int y0 = min(max((int)y0f, 0), H - 1);
    const int y1 = min(max((int)y1f, 0), H - 1);

    const float wa = (x1f - x) * (y1f - y);
    const float wb = (x1f - x) * (y - y0f);
    const float wc = (x - x0f) * (y1f - y);
    const float wd = (x - x0f) * (y - y0f);

    // each pixel = C floats = 8 float4s; lane handles quad q
    const float4* base = (const float4*)(in + (size_t)b * (H * W * C));
    const float4 Ia = base[(y0 * W + x0) * (C / 4) + q];
    const float4 Ib = base[(y1 * W + x0) * (C / 4) + q];
    const float4 Ic = base[(y0 * W + x1) * (C / 4) + q];
    const float4 Id = base[(y1 * W + x1) * (C / 4) + q];

    float4 o;
    o.x = wa * Ia.x + wb * Ib.x + wc * Ic.x + wd * Id.x;
    o.y = wa * Ia.y + wb * Ib.y + wc * Ic.y + wd * Id.y;
    o.z = wa * Ia.z + wb * Ib.z + wc * Ic.z + wd * Id.z;
    o.w = wa * Ia.w + wb * Ib.w + wc * Ic.w + wd * Id.w;

    ((float4*)out)[(size_t)p * (C / 4) + q] = o;
}

extern "C" void kernel_launch(void* const* d_in, const int* in_sizes, int n_in,
                              void* d_out, int out_size, void* d_ws, size_t ws_size,
                              hipStream_t stream) {
    const float* in    = (const float*)d_in[0];
    const float* theta = (const float*)d_in[1];
    float* out         = (float*)d_out;

    const int total_threads = B * OH * OW * (C / 4);  // 8 threads per pixel
    const int block = 256;
    const int grid  = total_threads / block;          // 32768, exact

    stn_bilinear_kernel<<<grid, block, 0, stream>>>(in, theta, out);
}